// Round 6
// baseline (114.926 us; speedup 1.0000x reference)
//
#include <hip/hip_runtime.h>

// CRF NLL on MI355X — round 16: r15 structure +
// (1) dead-chunk fast path: blocks with base<=0 write identity+Eg=0 and exit
//     (skip A-setup / burst / merge) — removes ~25% tail waste.
// (2) fp16 emissions: emS stored as _Float16 (ds_read_b64, half LDS bytes),
//     applied post-cvt via packed fp16 mul; esc from fp16 bits with -2
//     normalization margin (scf=2^(125-esc), esum+=esc+2) to bound B<2^14.

#define SS 512
#define TT 64
#define CC 16
#define KCH 32
#define START_TAG 62
#define END_TAG 63
#define LOG2E_F 1.44269504088896340736f
#define LN2_F 0.69314718055994530942f

#define WS_ECOL_OFF 8388608   // Pg: 64*16*4096*2B = 8 MB
#define MSTR 72               // merge-LDS row stride in halfs

typedef float v4f __attribute__((ext_vector_type(4)));
typedef _Float16 h4 __attribute__((ext_vector_type(4)));
typedef __fp16 c2 __attribute__((ext_vector_type(2)));
union H4u { h4 v; struct { c2 lo, hi; } p; };

// ---------------- per-step core: fp16-emission variant ----------------
__device__ __forceinline__ void estep(const h4 (&A)[4][4], h4 (&B)[4],
                                      const _Float16* __restrict__ emrow,
                                      int q, int& esum, int& esc) {
    v4f z = {0.f, 0.f, 0.f, 0.f};
    v4f D[4];
#pragma unroll
    for (int mt = 0; mt < 4; ++mt) {
        v4f a = __builtin_amdgcn_mfma_f32_16x16x16f16(A[mt][0], B[0], z, 0, 0, 0);
        a = __builtin_amdgcn_mfma_f32_16x16x16f16(A[mt][1], B[1], a, 0, 0, 0);
        v4f b = __builtin_amdgcn_mfma_f32_16x16x16f16(A[mt][2], B[2], z, 0, 0, 0);
        b = __builtin_amdgcn_mfma_f32_16x16x16f16(A[mt][3], B[3], b, 0, 0, 0);
        D[mt] = a + b;
    }
    esum += esc + 2;
    float scf = __uint_as_float((unsigned)(125 - esc) << 23);
#pragma unroll
    for (int mt = 0; mt < 4; ++mt) {
        v4f t = D[mt] * scf;
        H4u u;
        u.p.lo = __builtin_amdgcn_cvt_pkrtz(t.x, t.y);
        u.p.hi = __builtin_amdgcn_cvt_pkrtz(t.z, t.w);
        h4 em4 = *(const h4*)(emrow + 16 * mt + 4 * q);
        B[mt] = u.v * em4;   // packed fp16 mul
    }
    _Float16 b0 = B[0][0];
    unsigned short us = __builtin_bit_cast(unsigned short, b0);
    unsigned ui = (unsigned)__builtin_amdgcn_readfirstlane((int)us);
    esc = (int)((ui >> 10) & 31u) - 15;
}

// ---------------- chunk kernel: 4 sub-chains x 8 steps, fp16 LDS emissions ----------------
__global__ __launch_bounds__(256, 4)
void crf_chunks(const float* __restrict__ feats, const float* __restrict__ trans,
                const int* __restrict__ mask, unsigned short* __restrict__ Pg,
                int* __restrict__ Eg, float* __restrict__ out) {
    __shared__ __align__(16) _Float16 emS[KCH][TT];       // 4 KB emissions (fp16)
    __shared__ __align__(16) _Float16 mldB[TT * MSTR];
    __shared__ __align__(16) _Float16 mldD[TT * MSTR];
    __shared__ int ebuf[12];

    const int blk = blockIdx.x;
    const int chain = blk >> 4, c = blk & 15;
    const int tid = threadIdx.x;
    const int w = tid >> 6, l = tid & 63;
    const int n16 = l & 15, q = l >> 4;
    const int ncol = 16 * w + n16;

    if (blk == 0 && tid == 0) out[0] = 0.f;

    // chain length L (first: enables dead-chunk early-out)
    const int* mp = mask + chain * SS;
    int msum = 0;
#pragma unroll
    for (int k = 0; k < 8; ++k) msum += mp[k * 64 + l];
#pragma unroll
    for (int s_ = 1; s_ < 64; s_ <<= 1) msum += __shfl_xor(msum, s_, 64);
    const int L = msum;

    const int basei = (L - 1) - KCH * c;
    if (basei <= 0) {
        // fully dead chunk: product = identity, exponent 0; skip everything
        int r = tid >> 2, cb = tid & 3;
        unsigned short buf[16];
#pragma unroll
        for (int j = 0; j < 16; ++j)
            buf[j] = (16 * cb + j == r) ? (unsigned short)0x3C00 : (unsigned short)0;
        uint4* dst = (uint4*)(Pg + ((size_t)chain * CC + c) * 4096 + r * TT + cb * 16);
        dst[0] = *(const uint4*)(buf);
        dst[1] = *(const uint4*)(buf + 8);
        if (q == 0) Eg[(chain * CC + c) * TT + ncol] = 0;
        return;
    }

    // A = E^T stationary frags from trans
    h4 A[4][4];
#pragma unroll
    for (int mt = 0; mt < 4; ++mt)
#pragma unroll
        for (int ks = 0; ks < 4; ++ks) {
            h4 a;
#pragma unroll
            for (int e = 0; e < 4; ++e)
                a[e] = (_Float16)__builtin_amdgcn_exp2f(
                    trans[(16 * ks + 4 * q + e) * TT + 16 * mt + n16] * LOG2E_F);
            A[mt][ks] = a;
        }

    const int t0a = 1 + KCH * c;
    int nA = basei < 0 ? 0 : (basei > 8 ? 8 : basei);
    int nB = basei - 8 < 0 ? 0 : (basei - 8 > 8 ? 8 : basei - 8);
    int nC = basei - 16 < 0 ? 0 : (basei - 16 > 8 ? 8 : basei - 16);
    int nD = basei - 24 < 0 ? 0 : (basei - 24 > 8 ? 8 : basei - 24);

    // ---- burst-load emissions: 32 timesteps x 64 tags, exp2 -> fp16 LDS ----
    const float* fbase = feats + (size_t)chain * SS * TT;
#pragma unroll
    for (int k = 0; k < 2; ++k) {
        int idx = tid + 256 * k;      // 0..511
        int row = idx >> 4;           // 0..31
        int seg = idx & 15;           // 16B (f32) segment
        int t = t0a + row;
        t = t < SS ? t : SS - 1;
        v4f v = *(const v4f*)(fbase + (size_t)t * TT + 4 * seg);
        H4u u;
        u.p.lo = __builtin_amdgcn_cvt_pkrtz(__builtin_amdgcn_exp2f(v.x * LOG2E_F),
                                            __builtin_amdgcn_exp2f(v.y * LOG2E_F));
        u.p.hi = __builtin_amdgcn_cvt_pkrtz(__builtin_amdgcn_exp2f(v.z * LOG2E_F),
                                            __builtin_amdgcn_exp2f(v.w * LOG2E_F));
        *(h4*)(&emS[row][4 * seg]) = u.v;
    }

    // identity inits
    h4 Ba[4], Bb[4], Bc[4], Bd[4];
#pragma unroll
    for (int ks = 0; ks < 4; ++ks) {
        h4 b;
#pragma unroll
        for (int jj = 0; jj < 4; ++jj)
            b[jj] = (_Float16)((16 * ks + 4 * q + jj == ncol) ? 1.f : 0.f);
        Ba[ks] = b; Bb[ks] = b; Bc[ks] = b; Bd[ks] = b;
    }
    __syncthreads();  // emS ready

    int esA = 0, escA = 0, esB = 0, escB = 0;
    int esC = 0, escC = 0, esD = 0, escD = 0;

    if (nD == 8) {  // all four sub-chains full: branch-free hot path
        for (int r = 0; r < 4; ++r) {
            const int s0 = 2 * r, s1 = s0 + 1;
            estep(A, Ba, &emS[s0][0],      q, esA, escA);
            estep(A, Bb, &emS[8 + s0][0],  q, esB, escB);
            estep(A, Bc, &emS[16 + s0][0], q, esC, escC);
            estep(A, Bd, &emS[24 + s0][0], q, esD, escD);
            estep(A, Ba, &emS[s1][0],      q, esA, escA);
            estep(A, Bb, &emS[8 + s1][0],  q, esB, escB);
            estep(A, Bc, &emS[16 + s1][0], q, esC, escC);
            estep(A, Bd, &emS[24 + s1][0], q, esD, escD);
        }
    } else {  // boundary chunk: uniform-predicated
        for (int r = 0; r < 4; ++r) {
            const int s0 = 2 * r, s1 = s0 + 1;
            if (s0 < nA) estep(A, Ba, &emS[s0][0],      q, esA, escA);
            if (s0 < nB) estep(A, Bb, &emS[8 + s0][0],  q, esB, escB);
            if (s0 < nC) estep(A, Bc, &emS[16 + s0][0], q, esC, escC);
            if (s0 < nD) estep(A, Bd, &emS[24 + s0][0], q, esD, escD);
            if (s1 < nA) estep(A, Ba, &emS[s1][0],      q, esA, escA);
            if (s1 < nB) estep(A, Bb, &emS[8 + s1][0],  q, esB, escB);
            if (s1 < nC) estep(A, Bc, &emS[16 + s1][0], q, esC, escC);
            if (s1 < nD) estep(A, Bd, &emS[24 + s1][0], q, esD, escD);
        }
    }

    // ---- merge level 1: P1 = Hb*Ha, P2 = Hd*Hc (parallel) ----
    if (l == 0) { ebuf[w] = esB; ebuf[4 + w] = esD; }
    __syncthreads();
    const int eBmax = max(max(ebuf[0], ebuf[1]), max(ebuf[2], ebuf[3]));
    const int eDmax = max(max(ebuf[4], ebuf[5]), max(ebuf[6], ebuf[7]));
    {
        _Float16 sB = (_Float16)ldexpf(1.f, esB - eBmax);
        _Float16 sD = (_Float16)ldexpf(1.f, esD - eDmax);
        h4 s4B = {sB, sB, sB, sB}, s4D = {sD, sD, sD, sD};
#pragma unroll
        for (int ks = 0; ks < 4; ++ks) {
            h4 vb = Bb[ks] * s4B;
            h4 vd = Bd[ks] * s4D;
#pragma unroll
            for (int jj = 0; jj < 4; ++jj) {
                mldB[(16 * ks + 4 * q + jj) * MSTR + ncol] = vb[jj];
                mldD[(16 * ks + 4 * q + jj) * MSTR + ncol] = vd[jj];
            }
        }
    }
    __syncthreads();
    h4 AHb[4][4], AHd[4][4];
#pragma unroll
    for (int mt = 0; mt < 4; ++mt)
#pragma unroll
        for (int ks = 0; ks < 4; ++ks) {
            AHb[mt][ks] = *(const h4*)(mldB + (16 * mt + n16) * MSTR + 16 * ks + 4 * q);
            AHd[mt][ks] = *(const h4*)(mldD + (16 * mt + n16) * MSTR + 16 * ks + 4 * q);
        }
    v4f z = {0.f, 0.f, 0.f, 0.f};
    v4f P1[4], P2[4];
#pragma unroll
    for (int mt = 0; mt < 4; ++mt) {
        v4f a = __builtin_amdgcn_mfma_f32_16x16x16f16(AHb[mt][0], Ba[0], z, 0, 0, 0);
        a = __builtin_amdgcn_mfma_f32_16x16x16f16(AHb[mt][1], Ba[1], a, 0, 0, 0);
        v4f b = __builtin_amdgcn_mfma_f32_16x16x16f16(AHb[mt][2], Ba[2], z, 0, 0, 0);
        b = __builtin_amdgcn_mfma_f32_16x16x16f16(AHb[mt][3], Ba[3], b, 0, 0, 0);
        P1[mt] = a + b;
        v4f a2 = __builtin_amdgcn_mfma_f32_16x16x16f16(AHd[mt][0], Bc[0], z, 0, 0, 0);
        a2 = __builtin_amdgcn_mfma_f32_16x16x16f16(AHd[mt][1], Bc[1], a2, 0, 0, 0);
        v4f b2 = __builtin_amdgcn_mfma_f32_16x16x16f16(AHd[mt][2], Bc[2], z, 0, 0, 0);
        b2 = __builtin_amdgcn_mfma_f32_16x16x16f16(AHd[mt][3], Bc[3], b2, 0, 0, 0);
        P2[mt] = a2 + b2;
    }
    float m1 = 0.f, m2 = 0.f;
#pragma unroll
    for (int mt = 0; mt < 4; ++mt) {
        m1 = fmaxf(m1, fmaxf(fmaxf(P1[mt].x, P1[mt].y), fmaxf(P1[mt].z, P1[mt].w)));
        m2 = fmaxf(m2, fmaxf(fmaxf(P2[mt].x, P2[mt].y), fmaxf(P2[mt].z, P2[mt].w)));
    }
#pragma unroll
    for (int m = 1; m < 64; m <<= 1) {
        m1 = fmaxf(m1, __shfl_xor(m1, m, 64));
        m2 = fmaxf(m2, __shfl_xor(m2, m, 64));
    }
    unsigned u1 = (unsigned)__builtin_amdgcn_readfirstlane((int)__float_as_uint(m1));
    unsigned u2 = (unsigned)__builtin_amdgcn_readfirstlane((int)__float_as_uint(m2));
    const int e1c = u1 ? (int)((u1 >> 23) & 255u) - 127 : 0;
    const int e2c = u2 ? (int)((u2 >> 23) & 255u) - 127 : 0;
    const int e1 = esA + eBmax + e1c;
    const int e2 = esC + eDmax + e2c;
    h4 P1h[4], P2h[4];
    {
        float s1f = __uint_as_float((unsigned)(127 - e1c) << 23);
        float s2f = __uint_as_float((unsigned)(127 - e2c) << 23);
#pragma unroll
        for (int mt = 0; mt < 4; ++mt) {
            v4f q1 = P1[mt] * s1f;
            v4f q2 = P2[mt] * s2f;
            H4u ua, ub;
            ua.p.lo = __builtin_amdgcn_cvt_pkrtz(q1.x, q1.y);
            ua.p.hi = __builtin_amdgcn_cvt_pkrtz(q1.z, q1.w);
            ub.p.lo = __builtin_amdgcn_cvt_pkrtz(q2.x, q2.y);
            ub.p.hi = __builtin_amdgcn_cvt_pkrtz(q2.z, q2.w);
            P1h[mt] = ua.v;
            P2h[mt] = ub.v;
        }
    }

    // ---- merge level 2: R = P2 * P1 ----
    if (l == 0) ebuf[8 + w] = e2;
    __syncthreads();
    const int e2max = max(max(ebuf[8], ebuf[9]), max(ebuf[10], ebuf[11]));
    {
        _Float16 s2 = (_Float16)ldexpf(1.f, e2 - e2max);
        h4 s4 = {s2, s2, s2, s2};
#pragma unroll
        for (int mt = 0; mt < 4; ++mt) {
            h4 v = P2h[mt] * s4;
#pragma unroll
            for (int jj = 0; jj < 4; ++jj)
                mldB[(16 * mt + 4 * q + jj) * MSTR + ncol] = v[jj];
        }
    }
    __syncthreads();
    h4 AHp[4][4];
#pragma unroll
    for (int mt = 0; mt < 4; ++mt)
#pragma unroll
        for (int ks = 0; ks < 4; ++ks)
            AHp[mt][ks] = *(const h4*)(mldB + (16 * mt + n16) * MSTR + 16 * ks + 4 * q);
    h4 Rf[4];
#pragma unroll
    for (int mt = 0; mt < 4; ++mt) {
        v4f a = __builtin_amdgcn_mfma_f32_16x16x16f16(AHp[mt][0], P1h[0], z, 0, 0, 0);
        a = __builtin_amdgcn_mfma_f32_16x16x16f16(AHp[mt][1], P1h[1], a, 0, 0, 0);
        v4f b = __builtin_amdgcn_mfma_f32_16x16x16f16(AHp[mt][2], P1h[2], z, 0, 0, 0);
        b = __builtin_amdgcn_mfma_f32_16x16x16f16(AHp[mt][3], P1h[3], b, 0, 0, 0);
        v4f d = a + b;
        H4u u;
        u.p.lo = __builtin_amdgcn_cvt_pkrtz(d.x, d.y);
        u.p.hi = __builtin_amdgcn_cvt_pkrtz(d.z, d.w);
        Rf[mt] = u.v;
    }
    __syncthreads();  // mldD reads done; reuse for output staging
#pragma unroll
    for (int mt = 0; mt < 4; ++mt)
#pragma unroll
        for (int jj = 0; jj < 4; ++jj)
            mldD[(16 * mt + 4 * q + jj) * MSTR + ncol] = Rf[mt][jj];
    __syncthreads();
    {
        const size_t base_ = ((size_t)chain * CC + c) * 4096;
        int r = tid >> 2, cb = tid & 3;
        const uint4* src = (const uint4*)(mldD + r * MSTR + cb * 16);
        uint4* dst = (uint4*)(Pg + base_ + r * TT + cb * 16);
        dst[0] = src[0];
        dst[1] = src[1];
    }
    if (q == 0) Eg[(chain * CC + c) * TT + ncol] = e1 + e2max;
}

// ---------------- combine helpers ----------------
__device__ __forceinline__ int wimax64(int v) {
#pragma unroll
    for (int m = 1; m < 64; m <<= 1) v = max(v, __shfl_xor(v, m, 64));
    return v;
}
__device__ __forceinline__ float wfmax64(float v) {
#pragma unroll
    for (int m = 1; m < 64; m <<= 1) v = fmaxf(v, __shfl_xor(v, m, 64));
    return v;
}
__device__ __forceinline__ float wfsum64(float v) {
#pragma unroll
    for (int m = 1; m < 64; m <<= 1) v += __shfl_xor(v, m, 64);
    return v;
}
__device__ __forceinline__ int fexp(float m) {
    unsigned u = (unsigned)__builtin_amdgcn_readfirstlane((int)__float_as_uint(m));
    return u ? (int)((u >> 23) & 255u) - 127 : 0;
}
__device__ __forceinline__ void loadrow(uint4 (&h)[8], const unsigned short* __restrict__ PgC,
                                        int c, int l) {
    const uint4* rp = (const uint4*)((const _Float16*)PgC + (size_t)c * 4096) + l * 8;
#pragma unroll
    for (int i = 0; i < 8; ++i) h[i] = rp[i];
}
__device__ __forceinline__ void mvstep(const uint4 (&hv)[8], int e, float* __restrict__ xws,
                                       int l, float& x, int& exX) {
    int emax = wimax64(e);
    float xt = ldexpf(x, e - emax);
    xws[l] = xt;  // wave-local slot; same-wave ds_write->ds_read ordered by lgkmcnt
    float acc = 0.f;
#pragma unroll
    for (int i = 0; i < 8; ++i) {
        union { uint4 u; _Float16 hh[8]; } pv;
        pv.u = hv[i];
        v4f xa = *(const v4f*)(xws + 8 * i);
        v4f xb = *(const v4f*)(xws + 8 * i + 4);
        acc = __builtin_fmaf((float)pv.hh[0], xa.x, acc);
        acc = __builtin_fmaf((float)pv.hh[1], xa.y, acc);
        acc = __builtin_fmaf((float)pv.hh[2], xa.z, acc);
        acc = __builtin_fmaf((float)pv.hh[3], xa.w, acc);
        acc = __builtin_fmaf((float)pv.hh[4], xb.x, acc);
        acc = __builtin_fmaf((float)pv.hh[5], xb.y, acc);
        acc = __builtin_fmaf((float)pv.hh[6], xb.z, acc);
        acc = __builtin_fmaf((float)pv.hh[7], xb.w, acc);
    }
    float am = wfmax64(acc);
    int e0 = fexp(am);
    x = ldexpf(acc, -e0);
    exX += e0 + emax;
}

// ---------------- combine: pipelined matvec chain + gold ----------------
__global__ __launch_bounds__(256, 1)
void crf_combine(const float* __restrict__ feats, const float* __restrict__ trans,
                 const int* __restrict__ mask, const int* __restrict__ tags,
                 const unsigned short* __restrict__ Pg, const int* __restrict__ Eg,
                 float* __restrict__ out) {
    __shared__ __align__(16) float xsh[4][TT];
    __shared__ float gred[4];

    const int chain = blockIdx.x;
    const int tid = threadIdx.x;
    const int w = tid >> 6, l = tid & 63;
    const unsigned short* PgC = Pg + (size_t)chain * CC * 4096;
    const int* EgC = Eg + chain * CC * TT;
    const float* fbase = feats + (size_t)chain * SS * TT;

    // chain length L (per-wave, redundant)
    int msum = 0;
#pragma unroll
    for (int k = 0; k < 8; ++k) msum += mask[chain * SS + 64 * k + l];
#pragma unroll
    for (int m = 1; m < 64; m <<= 1) msum += __shfl_xor(msum, m, 64);
    const int L = msum;

    // gold partial: 2 positions per thread
    float g = 0.f;
#pragma unroll
    for (int rep = 0; rep < 2; ++rep) {
        int t = tid + rep * 256;
        if (t < L) {
            int cur = tags[chain * SS + t];
            int prev = t ? tags[chain * SS + t - 1] : START_TAG;
            g += fbase[(size_t)t * TT + cur] + trans[prev * TT + cur];
        }
    }
    g = wfsum64(g);
    if (l == 0) gred[w] = g;

    // p0 (all waves redundantly; identical values)
    float pl = fbase[l] + trans[START_TAG * TT + l];
    float M0 = wfmax64(pl);
    float x = __builtin_amdgcn_exp2f((pl - M0) * LOG2E_F);
    int exX = 0;

    // pipelined matvec chain over CC chunk matrices
    uint4 hA[8], hB[8];
    int eA, eB;
    loadrow(hA, PgC, 0, l);
    eA = EgC[0 * TT + l];
#pragma unroll
    for (int c = 0; c < CC; c += 2) {
        loadrow(hB, PgC, c + 1, l);
        eB = EgC[(c + 1) * TT + l];
        mvstep(hA, eA, &xsh[w][0], l, x, exX);
        if (c + 2 < CC) {
            loadrow(hA, PgC, c + 2, l);
            eA = EgC[(c + 2) * TT + l];
        }
        mvstep(hB, eB, &xsh[w][0], l, x, exX);
    }

    // final contraction: fwd = log( sum_l x[l]*exp(trans[l][END]) ) + exX*ln2 + M0
    float val = x * expf(trans[l * TT + END_TAG]);
    val = wfsum64(val);
    float fwd = logf(val) + (float)exX * LN2_F + M0;

    __syncthreads();  // gred ready
    if (tid == 0) {
        float gold = gred[0] + gred[1] + gred[2] + gred[3] +
                     trans[tags[chain * SS + L - 1] * TT + END_TAG];
        atomicAdd(out, fwd - gold);
    }
}

extern "C" void kernel_launch(void* const* d_in, const int* in_sizes, int n_in,
                              void* d_out, int out_size, void* d_ws, size_t ws_size,
                              hipStream_t stream) {
    const float* feats = (const float*)d_in[0];
    const float* trans = (const float*)d_in[1];
    const int*   mask  = (const int*)d_in[2];
    const int*   tags  = (const int*)d_in[3];
    float* out = (float*)d_out;
    unsigned short* Pg = (unsigned short*)d_ws;
    int*       Eg = (int*)((char*)d_ws + WS_ECOL_OFF);

    crf_chunks<<<dim3(64 * CC), dim3(256), 0, stream>>>(feats, trans, mask, Pg, Eg, out);
    crf_combine<<<dim3(64), dim3(256), 0, stream>>>(feats, trans, mask, tags, Pg, Eg, out);
}

// Round 7
// 101.631 us; speedup vs baseline: 1.1308x; 1.1308x over previous
//
#include <hip/hip_runtime.h>

// CRF NLL on MI355X — round 17: r16 structure, all 64x64 products converted
// to gfx950 mfma_f32_16x16x32_f16 (2xK): 8 MFMA/estep (was 16) and the
// a+b f32 adds are gone (-16 VALU/estep). A/B packed with the SAME
// (lane-group,elem)->k map (concat of the two K=16 fragments), so the
// contraction is exact regardless of the HW's internal k order.
// Dead-chunk fast path + fp16 LDS emissions + matvec combine unchanged.

#define SS 512
#define TT 64
#define CC 16
#define KCH 32
#define START_TAG 62
#define END_TAG 63
#define LOG2E_F 1.44269504088896340736f
#define LN2_F 0.69314718055994530942f

#define WS_ECOL_OFF 8388608   // Pg: 64*16*4096*2B = 8 MB
#define MSTR 72               // merge-LDS row stride in halfs

typedef float v4f __attribute__((ext_vector_type(4)));
typedef _Float16 h4 __attribute__((ext_vector_type(4)));
typedef _Float16 h8 __attribute__((ext_vector_type(8)));
typedef __fp16 c2 __attribute__((ext_vector_type(2)));
union H4u { h4 v; struct { c2 lo, hi; } p; };

__device__ __forceinline__ h8 cat(h4 a, h4 b) {
    return __builtin_shufflevector(a, b, 0, 1, 2, 3, 4, 5, 6, 7);
}

// ---------------- per-step core: 16x16x32 MFMA, fp16 emissions ----------------
__device__ __forceinline__ void estep(const h8 (&A)[4][2], h8 (&B)[2],
                                      const _Float16* __restrict__ emrow,
                                      int q, int& esum, int& esc) {
    v4f z = {0.f, 0.f, 0.f, 0.f};
    v4f D[4];
#pragma unroll
    for (int mt = 0; mt < 4; ++mt) {
        v4f a = __builtin_amdgcn_mfma_f32_16x16x32_f16(A[mt][0], B[0], z, 0, 0, 0);
        D[mt] = __builtin_amdgcn_mfma_f32_16x16x32_f16(A[mt][1], B[1], a, 0, 0, 0);
    }
    esum += esc + 2;
    float scf = __uint_as_float((unsigned)(125 - esc) << 23);
    h4 Bh[4];
#pragma unroll
    for (int mt = 0; mt < 4; ++mt) {
        v4f t = D[mt] * scf;
        H4u u;
        u.p.lo = __builtin_amdgcn_cvt_pkrtz(t.x, t.y);
        u.p.hi = __builtin_amdgcn_cvt_pkrtz(t.z, t.w);
        h4 em4 = *(const h4*)(emrow + 16 * mt + 4 * q);
        Bh[mt] = u.v * em4;   // packed fp16 mul
    }
    B[0] = cat(Bh[0], Bh[1]);
    B[1] = cat(Bh[2], Bh[3]);
    _Float16 b0 = Bh[0][0];
    unsigned short us = __builtin_bit_cast(unsigned short, b0);
    unsigned ui = (unsigned)__builtin_amdgcn_readfirstlane((int)us);
    esc = (int)((ui >> 10) & 31u) - 15;
}

// ---------------- chunk kernel: 4 sub-chains x 8 steps ----------------
__global__ __launch_bounds__(256, 4)
void crf_chunks(const float* __restrict__ feats, const float* __restrict__ trans,
                const int* __restrict__ mask, unsigned short* __restrict__ Pg,
                int* __restrict__ Eg, float* __restrict__ out) {
    __shared__ __align__(16) _Float16 emS[KCH][TT];       // 4 KB emissions (fp16)
    __shared__ __align__(16) _Float16 mldB[TT * MSTR];
    __shared__ __align__(16) _Float16 mldD[TT * MSTR];
    __shared__ int ebuf[12];

    const int blk = blockIdx.x;
    const int chain = blk >> 4, c = blk & 15;
    const int tid = threadIdx.x;
    const int w = tid >> 6, l = tid & 63;
    const int n16 = l & 15, q = l >> 4;
    const int ncol = 16 * w + n16;

    if (blk == 0 && tid == 0) out[0] = 0.f;

    // chain length L (first: enables dead-chunk early-out)
    const int* mp = mask + chain * SS;
    int msum = 0;
#pragma unroll
    for (int k = 0; k < 8; ++k) msum += mp[k * 64 + l];
#pragma unroll
    for (int s_ = 1; s_ < 64; s_ <<= 1) msum += __shfl_xor(msum, s_, 64);
    const int L = msum;

    const int basei = (L - 1) - KCH * c;
    if (basei <= 0) {
        // fully dead chunk: product = identity, exponent 0; skip everything
        int r = tid >> 2, cb = tid & 3;
        unsigned short buf[16];
#pragma unroll
        for (int j = 0; j < 16; ++j)
            buf[j] = (16 * cb + j == r) ? (unsigned short)0x3C00 : (unsigned short)0;
        uint4* dst = (uint4*)(Pg + ((size_t)chain * CC + c) * 4096 + r * TT + cb * 16);
        dst[0] = *(const uint4*)(buf);
        dst[1] = *(const uint4*)(buf + 8);
        if (q == 0) Eg[(chain * CC + c) * TT + ncol] = 0;
        return;
    }

    // A = E^T stationary frags, packed as h8 (K=32 slices, paired K=16 halves)
    h8 A8[4][2];
#pragma unroll
    for (int mt = 0; mt < 4; ++mt)
#pragma unroll
        for (int s = 0; s < 2; ++s) {
            h8 a;
#pragma unroll
            for (int e = 0; e < 8; ++e) {
                int ks = 2 * s + (e >> 2);
                a[e] = (_Float16)__builtin_amdgcn_exp2f(
                    trans[(16 * ks + 4 * q + (e & 3)) * TT + 16 * mt + n16] * LOG2E_F);
            }
            A8[mt][s] = a;
        }

    const int t0a = 1 + KCH * c;
    int nA = basei < 0 ? 0 : (basei > 8 ? 8 : basei);
    int nB = basei - 8 < 0 ? 0 : (basei - 8 > 8 ? 8 : basei - 8);
    int nC = basei - 16 < 0 ? 0 : (basei - 16 > 8 ? 8 : basei - 16);
    int nD = basei - 24 < 0 ? 0 : (basei - 24 > 8 ? 8 : basei - 24);

    // ---- burst-load emissions: 32 timesteps x 64 tags, exp2 -> fp16 LDS ----
    const float* fbase = feats + (size_t)chain * SS * TT;
#pragma unroll
    for (int k = 0; k < 2; ++k) {
        int idx = tid + 256 * k;      // 0..511
        int row = idx >> 4;           // 0..31
        int seg = idx & 15;           // 16B (f32) segment
        int t = t0a + row;
        t = t < SS ? t : SS - 1;
        v4f v = *(const v4f*)(fbase + (size_t)t * TT + 4 * seg);
        H4u u;
        u.p.lo = __builtin_amdgcn_cvt_pkrtz(__builtin_amdgcn_exp2f(v.x * LOG2E_F),
                                            __builtin_amdgcn_exp2f(v.y * LOG2E_F));
        u.p.hi = __builtin_amdgcn_cvt_pkrtz(__builtin_amdgcn_exp2f(v.z * LOG2E_F),
                                            __builtin_amdgcn_exp2f(v.w * LOG2E_F));
        *(h4*)(&emS[row][4 * seg]) = u.v;
    }

    // identity inits (h8: elem e -> row 16*(2s+(e>>2)) + 4q + (e&3))
    h8 Ba8[2], Bb8[2], Bc8[2], Bd8[2];
#pragma unroll
    for (int s = 0; s < 2; ++s) {
        h8 b;
#pragma unroll
        for (int e = 0; e < 8; ++e) {
            int row = 16 * (2 * s + (e >> 2)) + 4 * q + (e & 3);
            b[e] = (_Float16)((row == ncol) ? 1.f : 0.f);
        }
        Ba8[s] = b; Bb8[s] = b; Bc8[s] = b; Bd8[s] = b;
    }
    __syncthreads();  // emS ready

    int esA = 0, escA = 0, esB = 0, escB = 0;
    int esC = 0, escC = 0, esD = 0, escD = 0;

    if (nD == 8) {  // all four sub-chains full: branch-free hot path
        for (int r = 0; r < 4; ++r) {
            const int s0 = 2 * r, s1 = s0 + 1;
            estep(A8, Ba8, &emS[s0][0],      q, esA, escA);
            estep(A8, Bb8, &emS[8 + s0][0],  q, esB, escB);
            estep(A8, Bc8, &emS[16 + s0][0], q, esC, escC);
            estep(A8, Bd8, &emS[24 + s0][0], q, esD, escD);
            estep(A8, Ba8, &emS[s1][0],      q, esA, escA);
            estep(A8, Bb8, &emS[8 + s1][0],  q, esB, escB);
            estep(A8, Bc8, &emS[16 + s1][0], q, esC, escC);
            estep(A8, Bd8, &emS[24 + s1][0], q, esD, escD);
        }
    } else {  // boundary chunk: uniform-predicated
        for (int r = 0; r < 4; ++r) {
            const int s0 = 2 * r, s1 = s0 + 1;
            if (s0 < nA) estep(A8, Ba8, &emS[s0][0],      q, esA, escA);
            if (s0 < nB) estep(A8, Bb8, &emS[8 + s0][0],  q, esB, escB);
            if (s0 < nC) estep(A8, Bc8, &emS[16 + s0][0], q, esC, escC);
            if (s0 < nD) estep(A8, Bd8, &emS[24 + s0][0], q, esD, escD);
            if (s1 < nA) estep(A8, Ba8, &emS[s1][0],      q, esA, escA);
            if (s1 < nB) estep(A8, Bb8, &emS[8 + s1][0],  q, esB, escB);
            if (s1 < nC) estep(A8, Bc8, &emS[16 + s1][0], q, esC, escC);
            if (s1 < nD) estep(A8, Bd8, &emS[24 + s1][0], q, esD, escD);
        }
    }

    // ---- merge level 1: P1 = Hb*Ha, P2 = Hd*Hc (parallel) ----
    if (l == 0) { ebuf[w] = esB; ebuf[4 + w] = esD; }
    __syncthreads();
    const int eBmax = max(max(ebuf[0], ebuf[1]), max(ebuf[2], ebuf[3]));
    const int eDmax = max(max(ebuf[4], ebuf[5]), max(ebuf[6], ebuf[7]));
    {
        _Float16 sB = (_Float16)ldexpf(1.f, esB - eBmax);
        _Float16 sD = (_Float16)ldexpf(1.f, esD - eDmax);
        h8 s8B = {sB, sB, sB, sB, sB, sB, sB, sB};
        h8 s8D = {sD, sD, sD, sD, sD, sD, sD, sD};
#pragma unroll
        for (int s = 0; s < 2; ++s) {
            h8 vb = Bb8[s] * s8B;
            h8 vd = Bd8[s] * s8D;
#pragma unroll
            for (int e = 0; e < 8; ++e) {
                int row = 16 * (2 * s + (e >> 2)) + 4 * q + (e & 3);
                mldB[row * MSTR + ncol] = vb[e];
                mldD[row * MSTR + ncol] = vd[e];
            }
        }
    }
    __syncthreads();
    h8 AHb8[4][2], AHd8[4][2];
#pragma unroll
    for (int mt = 0; mt < 4; ++mt)
#pragma unroll
        for (int s = 0; s < 2; ++s) {
            const _Float16* rb = mldB + (16 * mt + n16) * MSTR;
            const _Float16* rd = mldD + (16 * mt + n16) * MSTR;
            h4 lob = *(const h4*)(rb + 16 * (2 * s) + 4 * q);
            h4 hib = *(const h4*)(rb + 16 * (2 * s + 1) + 4 * q);
            h4 lod = *(const h4*)(rd + 16 * (2 * s) + 4 * q);
            h4 hid = *(const h4*)(rd + 16 * (2 * s + 1) + 4 * q);
            AHb8[mt][s] = cat(lob, hib);
            AHd8[mt][s] = cat(lod, hid);
        }
    v4f z = {0.f, 0.f, 0.f, 0.f};
    v4f P1[4], P2[4];
#pragma unroll
    for (int mt = 0; mt < 4; ++mt) {
        v4f a = __builtin_amdgcn_mfma_f32_16x16x32_f16(AHb8[mt][0], Ba8[0], z, 0, 0, 0);
        P1[mt] = __builtin_amdgcn_mfma_f32_16x16x32_f16(AHb8[mt][1], Ba8[1], a, 0, 0, 0);
        v4f a2 = __builtin_amdgcn_mfma_f32_16x16x32_f16(AHd8[mt][0], Bc8[0], z, 0, 0, 0);
        P2[mt] = __builtin_amdgcn_mfma_f32_16x16x32_f16(AHd8[mt][1], Bc8[1], a2, 0, 0, 0);
    }
    float m1 = 0.f, m2 = 0.f;
#pragma unroll
    for (int mt = 0; mt < 4; ++mt) {
        m1 = fmaxf(m1, fmaxf(fmaxf(P1[mt].x, P1[mt].y), fmaxf(P1[mt].z, P1[mt].w)));
        m2 = fmaxf(m2, fmaxf(fmaxf(P2[mt].x, P2[mt].y), fmaxf(P2[mt].z, P2[mt].w)));
    }
#pragma unroll
    for (int m = 1; m < 64; m <<= 1) {
        m1 = fmaxf(m1, __shfl_xor(m1, m, 64));
        m2 = fmaxf(m2, __shfl_xor(m2, m, 64));
    }
    unsigned u1 = (unsigned)__builtin_amdgcn_readfirstlane((int)__float_as_uint(m1));
    unsigned u2 = (unsigned)__builtin_amdgcn_readfirstlane((int)__float_as_uint(m2));
    const int e1c = u1 ? (int)((u1 >> 23) & 255u) - 127 : 0;
    const int e2c = u2 ? (int)((u2 >> 23) & 255u) - 127 : 0;
    const int e1 = esA + eBmax + e1c;
    const int e2 = esC + eDmax + e2c;
    h4 p1h[4], p2h[4];
    {
        float s1f = __uint_as_float((unsigned)(127 - e1c) << 23);
        float s2f = __uint_as_float((unsigned)(127 - e2c) << 23);
#pragma unroll
        for (int mt = 0; mt < 4; ++mt) {
            v4f q1 = P1[mt] * s1f;
            v4f q2 = P2[mt] * s2f;
            H4u ua, ub;
            ua.p.lo = __builtin_amdgcn_cvt_pkrtz(q1.x, q1.y);
            ua.p.hi = __builtin_amdgcn_cvt_pkrtz(q1.z, q1.w);
            ub.p.lo = __builtin_amdgcn_cvt_pkrtz(q2.x, q2.y);
            ub.p.hi = __builtin_amdgcn_cvt_pkrtz(q2.z, q2.w);
            p1h[mt] = ua.v;
            p2h[mt] = ub.v;
        }
    }

    // ---- merge level 2: R = P2 * P1 ----
    if (l == 0) ebuf[8 + w] = e2;
    __syncthreads();
    const int e2max = max(max(ebuf[8], ebuf[9]), max(ebuf[10], ebuf[11]));
    {
        _Float16 s2 = (_Float16)ldexpf(1.f, e2 - e2max);
        h4 s4 = {s2, s2, s2, s2};
#pragma unroll
        for (int mt = 0; mt < 4; ++mt) {
            h4 v = p2h[mt] * s4;
#pragma unroll
            for (int jj = 0; jj < 4; ++jj)
                mldB[(16 * mt + 4 * q + jj) * MSTR + ncol] = v[jj];
        }
    }
    h8 P1h8[2];
    P1h8[0] = cat(p1h[0], p1h[1]);
    P1h8[1] = cat(p1h[2], p1h[3]);
    __syncthreads();
    h8 AHp8[4][2];
#pragma unroll
    for (int mt = 0; mt < 4; ++mt)
#pragma unroll
        for (int s = 0; s < 2; ++s) {
            const _Float16* rp = mldB + (16 * mt + n16) * MSTR;
            h4 lo = *(const h4*)(rp + 16 * (2 * s) + 4 * q);
            h4 hi = *(const h4*)(rp + 16 * (2 * s + 1) + 4 * q);
            AHp8[mt][s] = cat(lo, hi);
        }
    h4 Rf[4];
#pragma unroll
    for (int mt = 0; mt < 4; ++mt) {
        v4f a = __builtin_amdgcn_mfma_f32_16x16x32_f16(AHp8[mt][0], P1h8[0], z, 0, 0, 0);
        v4f d = __builtin_amdgcn_mfma_f32_16x16x32_f16(AHp8[mt][1], P1h8[1], a, 0, 0, 0);
        H4u u;
        u.p.lo = __builtin_amdgcn_cvt_pkrtz(d.x, d.y);
        u.p.hi = __builtin_amdgcn_cvt_pkrtz(d.z, d.w);
        Rf[mt] = u.v;
    }
    __syncthreads();  // mldD reads done; reuse for output staging
#pragma unroll
    for (int mt = 0; mt < 4; ++mt)
#pragma unroll
        for (int jj = 0; jj < 4; ++jj)
            mldD[(16 * mt + 4 * q + jj) * MSTR + ncol] = Rf[mt][jj];
    __syncthreads();
    {
        const size_t base_ = ((size_t)chain * CC + c) * 4096;
        int r = tid >> 2, cb = tid & 3;
        const uint4* src = (const uint4*)(mldD + r * MSTR + cb * 16);
        uint4* dst = (uint4*)(Pg + base_ + r * TT + cb * 16);
        dst[0] = src[0];
        dst[1] = src[1];
    }
    if (q == 0) Eg[(chain * CC + c) * TT + ncol] = e1 + e2max;
}

// ---------------- combine helpers ----------------
__device__ __forceinline__ int wimax64(int v) {
#pragma unroll
    for (int m = 1; m < 64; m <<= 1) v = max(v, __shfl_xor(v, m, 64));
    return v;
}
__device__ __forceinline__ float wfmax64(float v) {
#pragma unroll
    for (int m = 1; m < 64; m <<= 1) v = fmaxf(v, __shfl_xor(v, m, 64));
    return v;
}
__device__ __forceinline__ float wfsum64(float v) {
#pragma unroll
    for (int m = 1; m < 64; m <<= 1) v += __shfl_xor(v, m, 64);
    return v;
}
__device__ __forceinline__ int fexp(float m) {
    unsigned u = (unsigned)__builtin_amdgcn_readfirstlane((int)__float_as_uint(m));
    return u ? (int)((u >> 23) & 255u) - 127 : 0;
}
__device__ __forceinline__ void loadrow(uint4 (&h)[8], const unsigned short* __restrict__ PgC,
                                        int c, int l) {
    const uint4* rp = (const uint4*)((const _Float16*)PgC + (size_t)c * 4096) + l * 8;
#pragma unroll
    for (int i = 0; i < 8; ++i) h[i] = rp[i];
}
__device__ __forceinline__ void mvstep(const uint4 (&hv)[8], int e, float* __restrict__ xws,
                                       int l, float& x, int& exX) {
    int emax = wimax64(e);
    float xt = ldexpf(x, e - emax);
    xws[l] = xt;  // wave-local slot; same-wave ds_write->ds_read ordered by lgkmcnt
    float acc = 0.f;
#pragma unroll
    for (int i = 0; i < 8; ++i) {
        union { uint4 u; _Float16 hh[8]; } pv;
        pv.u = hv[i];
        v4f xa = *(const v4f*)(xws + 8 * i);
        v4f xb = *(const v4f*)(xws + 8 * i + 4);
        acc = __builtin_fmaf((float)pv.hh[0], xa.x, acc);
        acc = __builtin_fmaf((float)pv.hh[1], xa.y, acc);
        acc = __builtin_fmaf((float)pv.hh[2], xa.z, acc);
        acc = __builtin_fmaf((float)pv.hh[3], xa.w, acc);
        acc = __builtin_fmaf((float)pv.hh[4], xb.x, acc);
        acc = __builtin_fmaf((float)pv.hh[5], xb.y, acc);
        acc = __builtin_fmaf((float)pv.hh[6], xb.z, acc);
        acc = __builtin_fmaf((float)pv.hh[7], xb.w, acc);
    }
    float am = wfmax64(acc);
    int e0 = fexp(am);
    x = ldexpf(acc, -e0);
    exX += e0 + emax;
}

// ---------------- combine: pipelined matvec chain + gold ----------------
__global__ __launch_bounds__(256, 1)
void crf_combine(const float* __restrict__ feats, const float* __restrict__ trans,
                 const int* __restrict__ mask, const int* __restrict__ tags,
                 const unsigned short* __restrict__ Pg, const int* __restrict__ Eg,
                 float* __restrict__ out) {
    __shared__ __align__(16) float xsh[4][TT];
    __shared__ float gred[4];

    const int chain = blockIdx.x;
    const int tid = threadIdx.x;
    const int w = tid >> 6, l = tid & 63;
    const unsigned short* PgC = Pg + (size_t)chain * CC * 4096;
    const int* EgC = Eg + chain * CC * TT;
    const float* fbase = feats + (size_t)chain * SS * TT;

    // chain length L (per-wave, redundant)
    int msum = 0;
#pragma unroll
    for (int k = 0; k < 8; ++k) msum += mask[chain * SS + 64 * k + l];
#pragma unroll
    for (int m = 1; m < 64; m <<= 1) msum += __shfl_xor(msum, m, 64);
    const int L = msum;

    // gold partial: 2 positions per thread
    float g = 0.f;
#pragma unroll
    for (int rep = 0; rep < 2; ++rep) {
        int t = tid + rep * 256;
        if (t < L) {
            int cur = tags[chain * SS + t];
            int prev = t ? tags[chain * SS + t - 1] : START_TAG;
            g += fbase[(size_t)t * TT + cur] + trans[prev * TT + cur];
        }
    }
    g = wfsum64(g);
    if (l == 0) gred[w] = g;

    // p0 (all waves redundantly; identical values)
    float pl = fbase[l] + trans[START_TAG * TT + l];
    float M0 = wfmax64(pl);
    float x = __builtin_amdgcn_exp2f((pl - M0) * LOG2E_F);
    int exX = 0;

    // pipelined matvec chain over CC chunk matrices
    uint4 hA[8], hB[8];
    int eA, eB;
    loadrow(hA, PgC, 0, l);
    eA = EgC[0 * TT + l];
#pragma unroll
    for (int c = 0; c < CC; c += 2) {
        loadrow(hB, PgC, c + 1, l);
        eB = EgC[(c + 1) * TT + l];
        mvstep(hA, eA, &xsh[w][0], l, x, exX);
        if (c + 2 < CC) {
            loadrow(hA, PgC, c + 2, l);
            eA = EgC[(c + 2) * TT + l];
        }
        mvstep(hB, eB, &xsh[w][0], l, x, exX);
    }

    // final contraction: fwd = log( sum_l x[l]*exp(trans[l][END]) ) + exX*ln2 + M0
    float val = x * expf(trans[l * TT + END_TAG]);
    val = wfsum64(val);
    float fwd = logf(val) + (float)exX * LN2_F + M0;

    __syncthreads();  // gred ready
    if (tid == 0) {
        float gold = gred[0] + gred[1] + gred[2] + gred[3] +
                     trans[tags[chain * SS + L - 1] * TT + END_TAG];
        atomicAdd(out, fwd - gold);
    }
}

extern "C" void kernel_launch(void* const* d_in, const int* in_sizes, int n_in,
                              void* d_out, int out_size, void* d_ws, size_t ws_size,
                              hipStream_t stream) {
    const float* feats = (const float*)d_in[0];
    const float* trans = (const float*)d_in[1];
    const int*   mask  = (const int*)d_in[2];
    const int*   tags  = (const int*)d_in[3];
    float* out = (float*)d_out;
    unsigned short* Pg = (unsigned short*)d_ws;
    int*       Eg = (int*)((char*)d_ws + WS_ECOL_OFF);

    crf_chunks<<<dim3(64 * CC), dim3(256), 0, stream>>>(feats, trans, mask, Pg, Eg, out);
    crf_combine<<<dim3(64), dim3(256), 0, stream>>>(feats, trans, mask, tags, Pg, Eg, out);
}

// Round 9
// 101.545 us; speedup vs baseline: 1.1318x; 1.0008x over previous
//
#include <hip/hip_runtime.h>

// CRF NLL on MI355X — round 19: r18 with the estep overflow bug fixed.
// estep reverted to r17-proven form: renorm scale applied in f32 BEFORE the
// fp16 convert (cvt input bounded); esc read from fp16 bits. r18's per-chunk
// scalar exponent (pre-scaled R columns + one int per chunk, simplified
// combine mvstep without wave-reduce/ldexp) is kept — it was not the bug.

#define SS 512
#define TT 64
#define CC 16
#define KCH 32
#define START_TAG 62
#define END_TAG 63
#define LOG2E_F 1.44269504088896340736f
#define LN2_F 0.69314718055994530942f

#define WS_ECOL_OFF 8388608   // Pg: 64*16*4096*2B = 8 MB; Eg: 64*16 ints
#define MSTR 72               // merge-LDS row stride in halfs

typedef float v4f __attribute__((ext_vector_type(4)));
typedef _Float16 h4 __attribute__((ext_vector_type(4)));
typedef _Float16 h8 __attribute__((ext_vector_type(8)));
typedef __fp16 c2 __attribute__((ext_vector_type(2)));
union H4u { h4 v; struct { c2 lo, hi; } p; };

__device__ __forceinline__ h8 cat(h4 a, h4 b) {
    return __builtin_shufflevector(a, b, 0, 1, 2, 3, 4, 5, 6, 7);
}
__device__ __forceinline__ _Float16 h16_pow2(int e) {
    // 2^e as fp16 (normal range only; clamp below to 0)
    int d = e + 15;
    unsigned short sb = d > 0 ? (unsigned short)(d << 10) : (unsigned short)0;
    return __builtin_bit_cast(_Float16, sb);
}

// ---------------- per-step core: 16x16x32 MFMA, f32 pre-scale (r17-proven) ----------------
__device__ __forceinline__ void estep(const h8 (&A)[4][2], h8 (&B)[2],
                                      const _Float16* __restrict__ emrow,
                                      int q, int& esum, int& esc) {
    v4f z = {0.f, 0.f, 0.f, 0.f};
    v4f D[4];
#pragma unroll
    for (int mt = 0; mt < 4; ++mt) {
        v4f a = __builtin_amdgcn_mfma_f32_16x16x32_f16(A[mt][0], B[0], z, 0, 0, 0);
        D[mt] = __builtin_amdgcn_mfma_f32_16x16x32_f16(A[mt][1], B[1], a, 0, 0, 0);
    }
    esum += esc + 2;
    float scf = __uint_as_float((unsigned)(125 - esc) << 23);
    h4 Bh[4];
#pragma unroll
    for (int mt = 0; mt < 4; ++mt) {
        v4f t = D[mt] * scf;
        H4u u;
        u.p.lo = __builtin_amdgcn_cvt_pkrtz(t.x, t.y);
        u.p.hi = __builtin_amdgcn_cvt_pkrtz(t.z, t.w);
        h4 em4 = *(const h4*)(emrow + 16 * mt + 4 * q);
        Bh[mt] = u.v * em4;   // packed fp16 mul
    }
    B[0] = cat(Bh[0], Bh[1]);
    B[1] = cat(Bh[2], Bh[3]);
    _Float16 b0 = Bh[0][0];
    unsigned short us = __builtin_bit_cast(unsigned short, b0);
    unsigned ui = (unsigned)__builtin_amdgcn_readfirstlane((int)us);
    esc = (int)((ui >> 10) & 31u) - 15;
}

// ---------------- chunk kernel: 4 sub-chains x 8 steps ----------------
__global__ __launch_bounds__(256, 4)
void crf_chunks(const float* __restrict__ feats, const float* __restrict__ trans,
                const int* __restrict__ mask, unsigned short* __restrict__ Pg,
                int* __restrict__ Eg, float* __restrict__ out) {
    __shared__ __align__(16) _Float16 emS[KCH][TT];       // 4 KB emissions (fp16)
    __shared__ __align__(16) _Float16 mldB[TT * MSTR];
    __shared__ __align__(16) _Float16 mldD[TT * MSTR];
    __shared__ int ebuf[12];
    __shared__ int ecol4[4];

    const int blk = blockIdx.x;
    const int chain = blk >> 4, c = blk & 15;
    const int tid = threadIdx.x;
    const int w = tid >> 6, l = tid & 63;
    const int n16 = l & 15, q = l >> 4;
    const int ncol = 16 * w + n16;

    if (blk == 0 && tid == 0) out[0] = 0.f;

    // chain length L (first: enables dead-chunk early-out)
    const int* mp = mask + chain * SS;
    int msum = 0;
#pragma unroll
    for (int k = 0; k < 8; ++k) msum += mp[k * 64 + l];
#pragma unroll
    for (int s_ = 1; s_ < 64; s_ <<= 1) msum += __shfl_xor(msum, s_, 64);
    const int L = msum;

    const int basei = (L - 1) - KCH * c;
    if (basei <= 0) {
        // fully dead chunk: product = identity, exponent 0; skip everything
        int r = tid >> 2, cb = tid & 3;
        unsigned short buf[16];
#pragma unroll
        for (int j = 0; j < 16; ++j)
            buf[j] = (16 * cb + j == r) ? (unsigned short)0x3C00 : (unsigned short)0;
        uint4* dst = (uint4*)(Pg + ((size_t)chain * CC + c) * 4096 + r * TT + cb * 16);
        dst[0] = *(const uint4*)(buf);
        dst[1] = *(const uint4*)(buf + 8);
        if (tid == 0) Eg[chain * CC + c] = 0;
        return;
    }

    // A = E^T stationary frags, packed as h8 (K=32 slices, paired K=16 halves)
    h8 A8[4][2];
#pragma unroll
    for (int mt = 0; mt < 4; ++mt)
#pragma unroll
        for (int s = 0; s < 2; ++s) {
            h8 a;
#pragma unroll
            for (int e = 0; e < 8; ++e) {
                int ks = 2 * s + (e >> 2);
                a[e] = (_Float16)__builtin_amdgcn_exp2f(
                    trans[(16 * ks + 4 * q + (e & 3)) * TT + 16 * mt + n16] * LOG2E_F);
            }
            A8[mt][s] = a;
        }

    const int t0a = 1 + KCH * c;
    int nA = basei < 0 ? 0 : (basei > 8 ? 8 : basei);
    int nB = basei - 8 < 0 ? 0 : (basei - 8 > 8 ? 8 : basei - 8);
    int nC = basei - 16 < 0 ? 0 : (basei - 16 > 8 ? 8 : basei - 16);
    int nD = basei - 24 < 0 ? 0 : (basei - 24 > 8 ? 8 : basei - 24);

    // ---- burst-load emissions: 32 timesteps x 64 tags, exp2 -> fp16 LDS ----
    const float* fbase = feats + (size_t)chain * SS * TT;
#pragma unroll
    for (int k = 0; k < 2; ++k) {
        int idx = tid + 256 * k;      // 0..511
        int row = idx >> 4;           // 0..31
        int seg = idx & 15;           // 16B (f32) segment
        int t = t0a + row;
        t = t < SS ? t : SS - 1;
        v4f v = *(const v4f*)(fbase + (size_t)t * TT + 4 * seg);
        H4u u;
        u.p.lo = __builtin_amdgcn_cvt_pkrtz(__builtin_amdgcn_exp2f(v.x * LOG2E_F),
                                            __builtin_amdgcn_exp2f(v.y * LOG2E_F));
        u.p.hi = __builtin_amdgcn_cvt_pkrtz(__builtin_amdgcn_exp2f(v.z * LOG2E_F),
                                            __builtin_amdgcn_exp2f(v.w * LOG2E_F));
        *(h4*)(&emS[row][4 * seg]) = u.v;
    }

    // identity inits (h8: elem e -> row 16*(2s+(e>>2)) + 4q + (e&3))
    h8 Ba8[2], Bb8[2], Bc8[2], Bd8[2];
#pragma unroll
    for (int s = 0; s < 2; ++s) {
        h8 b;
#pragma unroll
        for (int e = 0; e < 8; ++e) {
            int row = 16 * (2 * s + (e >> 2)) + 4 * q + (e & 3);
            b[e] = (_Float16)((row == ncol) ? 1.f : 0.f);
        }
        Ba8[s] = b; Bb8[s] = b; Bc8[s] = b; Bd8[s] = b;
    }
    __syncthreads();  // emS ready

    int esA = 0, escA = 0, esB = 0, escB = 0;
    int esC = 0, escC = 0, esD = 0, escD = 0;

    if (nD == 8) {  // all four sub-chains full: branch-free hot path
        for (int r = 0; r < 4; ++r) {
            const int s0 = 2 * r, s1 = s0 + 1;
            estep(A8, Ba8, &emS[s0][0],      q, esA, escA);
            estep(A8, Bb8, &emS[8 + s0][0],  q, esB, escB);
            estep(A8, Bc8, &emS[16 + s0][0], q, esC, escC);
            estep(A8, Bd8, &emS[24 + s0][0], q, esD, escD);
            estep(A8, Ba8, &emS[s1][0],      q, esA, escA);
            estep(A8, Bb8, &emS[8 + s1][0],  q, esB, escB);
            estep(A8, Bc8, &emS[16 + s1][0], q, esC, escC);
            estep(A8, Bd8, &emS[24 + s1][0], q, esD, escD);
        }
    } else {  // boundary chunk: uniform-predicated
        for (int r = 0; r < 4; ++r) {
            const int s0 = 2 * r, s1 = s0 + 1;
            if (s0 < nA) estep(A8, Ba8, &emS[s0][0],      q, esA, escA);
            if (s0 < nB) estep(A8, Bb8, &emS[8 + s0][0],  q, esB, escB);
            if (s0 < nC) estep(A8, Bc8, &emS[16 + s0][0], q, esC, escC);
            if (s0 < nD) estep(A8, Bd8, &emS[24 + s0][0], q, esD, escD);
            if (s1 < nA) estep(A8, Ba8, &emS[s1][0],      q, esA, escA);
            if (s1 < nB) estep(A8, Bb8, &emS[8 + s1][0],  q, esB, escB);
            if (s1 < nC) estep(A8, Bc8, &emS[16 + s1][0], q, esC, escC);
            if (s1 < nD) estep(A8, Bd8, &emS[24 + s1][0], q, esD, escD);
        }
    }

    // ---- merge level 1: P1 = Hb*Ha, P2 = Hd*Hc (parallel) ----
    if (l == 0) { ebuf[w] = esB; ebuf[4 + w] = esD; }
    __syncthreads();
    const int eBmax = max(max(ebuf[0], ebuf[1]), max(ebuf[2], ebuf[3]));
    const int eDmax = max(max(ebuf[4], ebuf[5]), max(ebuf[6], ebuf[7]));
    {
        _Float16 sB = (_Float16)ldexpf(1.f, esB - eBmax);
        _Float16 sD = (_Float16)ldexpf(1.f, esD - eDmax);
        h8 s8B = {sB, sB, sB, sB, sB, sB, sB, sB};
        h8 s8D = {sD, sD, sD, sD, sD, sD, sD, sD};
#pragma unroll
        for (int s = 0; s < 2; ++s) {
            h8 vb = Bb8[s] * s8B;
            h8 vd = Bd8[s] * s8D;
#pragma unroll
            for (int e = 0; e < 8; ++e) {
                int row = 16 * (2 * s + (e >> 2)) + 4 * q + (e & 3);
                mldB[row * MSTR + ncol] = vb[e];
                mldD[row * MSTR + ncol] = vd[e];
            }
        }
    }
    __syncthreads();
    h8 AHb8[4][2], AHd8[4][2];
#pragma unroll
    for (int mt = 0; mt < 4; ++mt)
#pragma unroll
        for (int s = 0; s < 2; ++s) {
            const _Float16* rb = mldB + (16 * mt + n16) * MSTR;
            const _Float16* rd = mldD + (16 * mt + n16) * MSTR;
            h4 lob = *(const h4*)(rb + 16 * (2 * s) + 4 * q);
            h4 hib = *(const h4*)(rb + 16 * (2 * s + 1) + 4 * q);
            h4 lod = *(const h4*)(rd + 16 * (2 * s) + 4 * q);
            h4 hid = *(const h4*)(rd + 16 * (2 * s + 1) + 4 * q);
            AHb8[mt][s] = cat(lob, hib);
            AHd8[mt][s] = cat(lod, hid);
        }
    v4f z = {0.f, 0.f, 0.f, 0.f};
    v4f P1[4], P2[4];
#pragma unroll
    for (int mt = 0; mt < 4; ++mt) {
        v4f a = __builtin_amdgcn_mfma_f32_16x16x32_f16(AHb8[mt][0], Ba8[0], z, 0, 0, 0);
        P1[mt] = __builtin_amdgcn_mfma_f32_16x16x32_f16(AHb8[mt][1], Ba8[1], a, 0, 0, 0);
        v4f a2 = __builtin_amdgcn_mfma_f32_16x16x32_f16(AHd8[mt][0], Bc8[0], z, 0, 0, 0);
        P2[mt] = __builtin_amdgcn_mfma_f32_16x16x32_f16(AHd8[mt][1], Bc8[1], a2, 0, 0, 0);
    }
    float m1 = 0.f, m2 = 0.f;
#pragma unroll
    for (int mt = 0; mt < 4; ++mt) {
        m1 = fmaxf(m1, fmaxf(fmaxf(P1[mt].x, P1[mt].y), fmaxf(P1[mt].z, P1[mt].w)));
        m2 = fmaxf(m2, fmaxf(fmaxf(P2[mt].x, P2[mt].y), fmaxf(P2[mt].z, P2[mt].w)));
    }
#pragma unroll
    for (int m = 1; m < 64; m <<= 1) {
        m1 = fmaxf(m1, __shfl_xor(m1, m, 64));
        m2 = fmaxf(m2, __shfl_xor(m2, m, 64));
    }
    unsigned u1 = (unsigned)__builtin_amdgcn_readfirstlane((int)__float_as_uint(m1));
    unsigned u2 = (unsigned)__builtin_amdgcn_readfirstlane((int)__float_as_uint(m2));
    const int e1c = u1 ? (int)((u1 >> 23) & 255u) - 127 : 0;
    const int e2c = u2 ? (int)((u2 >> 23) & 255u) - 127 : 0;
    const int e1 = esA + eBmax + e1c;
    const int e2 = esC + eDmax + e2c;
    h4 p1h[4], p2h[4];
    {
        float s1f = __uint_as_float((unsigned)(127 - e1c) << 23);
        float s2f = __uint_as_float((unsigned)(127 - e2c) << 23);
#pragma unroll
        for (int mt = 0; mt < 4; ++mt) {
            v4f q1 = P1[mt] * s1f;
            v4f q2 = P2[mt] * s2f;
            H4u ua, ub;
            ua.p.lo = __builtin_amdgcn_cvt_pkrtz(q1.x, q1.y);
            ua.p.hi = __builtin_amdgcn_cvt_pkrtz(q1.z, q1.w);
            ub.p.lo = __builtin_amdgcn_cvt_pkrtz(q2.x, q2.y);
            ub.p.hi = __builtin_amdgcn_cvt_pkrtz(q2.z, q2.w);
            p1h[mt] = ua.v;
            p2h[mt] = ub.v;
        }
    }

    // ---- merge level 2: R = P2 * P1 ----
    if (l == 0) ebuf[8 + w] = e2;
    __syncthreads();
    const int e2max = max(max(ebuf[8], ebuf[9]), max(ebuf[10], ebuf[11]));
    {
        _Float16 s2 = (_Float16)ldexpf(1.f, e2 - e2max);
        h4 s4 = {s2, s2, s2, s2};
#pragma unroll
        for (int mt = 0; mt < 4; ++mt) {
            h4 v = p2h[mt] * s4;
#pragma unroll
            for (int jj = 0; jj < 4; ++jj)
                mldB[(16 * mt + 4 * q + jj) * MSTR + ncol] = v[jj];
        }
    }
    h8 P1h8[2];
    P1h8[0] = cat(p1h[0], p1h[1]);
    P1h8[1] = cat(p1h[2], p1h[3]);
    __syncthreads();
    h8 AHp8[4][2];
#pragma unroll
    for (int mt = 0; mt < 4; ++mt)
#pragma unroll
        for (int s = 0; s < 2; ++s) {
            const _Float16* rp = mldB + (16 * mt + n16) * MSTR;
            h4 lo = *(const h4*)(rp + 16 * (2 * s) + 4 * q);
            h4 hi = *(const h4*)(rp + 16 * (2 * s + 1) + 4 * q);
            AHp8[mt][s] = cat(lo, hi);
        }
    h4 Rf[4];
#pragma unroll
    for (int mt = 0; mt < 4; ++mt) {
        v4f a = __builtin_amdgcn_mfma_f32_16x16x32_f16(AHp8[mt][0], P1h8[0], z, 0, 0, 0);
        v4f d = __builtin_amdgcn_mfma_f32_16x16x32_f16(AHp8[mt][1], P1h8[1], a, 0, 0, 0);
        H4u u;
        u.p.lo = __builtin_amdgcn_cvt_pkrtz(d.x, d.y);
        u.p.hi = __builtin_amdgcn_cvt_pkrtz(d.z, d.w);
        Rf[mt] = u.v;
    }

    // ---- per-chunk exponent unification: scale columns to block max ----
    const int ecol = e1 + e2max;           // per-wave uniform column exponent
    if (l == 0) ecol4[w] = ecol;
    __syncthreads();  // also covers: mldD reads (AHd) long done; reuse below
    const int eblk = max(max(ecol4[0], ecol4[1]), max(ecol4[2], ecol4[3]));
    {
        _Float16 sR = h16_pow2(ecol - eblk);   // <=1 exact pow2 (0 if < 2^-15)
        h4 sR4 = {sR, sR, sR, sR};
#pragma unroll
        for (int mt = 0; mt < 4; ++mt) {
            h4 v = Rf[mt] * sR4;
#pragma unroll
            for (int jj = 0; jj < 4; ++jj)
                mldD[(16 * mt + 4 * q + jj) * MSTR + ncol] = v[jj];
        }
    }
    __syncthreads();
    {
        const size_t base_ = ((size_t)chain * CC + c) * 4096;
        int r = tid >> 2, cb = tid & 3;
        const uint4* src = (const uint4*)(mldD + r * MSTR + cb * 16);
        uint4* dst = (uint4*)(Pg + base_ + r * TT + cb * 16);
        dst[0] = src[0];
        dst[1] = src[1];
    }
    if (tid == 0) Eg[chain * CC + c] = eblk;
}

// ---------------- combine helpers ----------------
__device__ __forceinline__ float wfmax64(float v) {
#pragma unroll
    for (int m = 1; m < 64; m <<= 1) v = fmaxf(v, __shfl_xor(v, m, 64));
    return v;
}
__device__ __forceinline__ float wfsum64(float v) {
#pragma unroll
    for (int m = 1; m < 64; m <<= 1) v += __shfl_xor(v, m, 64);
    return v;
}
__device__ __forceinline__ int fexp(float m) {
    unsigned u = (unsigned)__builtin_amdgcn_readfirstlane((int)__float_as_uint(m));
    return u ? (int)((u >> 23) & 255u) - 127 : 0;
}
__device__ __forceinline__ void loadrow(uint4 (&h)[8], const unsigned short* __restrict__ PgC,
                                        int c, int l) {
    const uint4* rp = (const uint4*)((const _Float16*)PgC + (size_t)c * 4096) + l * 8;
#pragma unroll
    for (int i = 0; i < 8; ++i) h[i] = rp[i];
}
__device__ __forceinline__ void mvstep(const uint4 (&hv)[8], int eb, float* __restrict__ xws,
                                       int l, float& x, int& exX) {
    xws[l] = x;  // wave-local slot; same-wave ds_write->ds_read ordered by lgkmcnt
    float acc = 0.f;
#pragma unroll
    for (int i = 0; i < 8; ++i) {
        union { uint4 u; _Float16 hh[8]; } pv;
        pv.u = hv[i];
        v4f xa = *(const v4f*)(xws + 8 * i);
        v4f xb = *(const v4f*)(xws + 8 * i + 4);
        acc = __builtin_fmaf((float)pv.hh[0], xa.x, acc);
        acc = __builtin_fmaf((float)pv.hh[1], xa.y, acc);
        acc = __builtin_fmaf((float)pv.hh[2], xa.z, acc);
        acc = __builtin_fmaf((float)pv.hh[3], xa.w, acc);
        acc = __builtin_fmaf((float)pv.hh[4], xb.x, acc);
        acc = __builtin_fmaf((float)pv.hh[5], xb.y, acc);
        acc = __builtin_fmaf((float)pv.hh[6], xb.z, acc);
        acc = __builtin_fmaf((float)pv.hh[7], xb.w, acc);
    }
    float am = wfmax64(acc);
    int e0 = fexp(am);
    x = ldexpf(acc, -e0);
    exX += e0 + eb;
}

// ---------------- combine: pipelined matvec chain + gold ----------------
__global__ __launch_bounds__(256, 1)
void crf_combine(const float* __restrict__ feats, const float* __restrict__ trans,
                 const int* __restrict__ mask, const int* __restrict__ tags,
                 const unsigned short* __restrict__ Pg, const int* __restrict__ Eg,
                 float* __restrict__ out) {
    __shared__ __align__(16) float xsh[4][TT];
    __shared__ float gred[4];

    const int chain = blockIdx.x;
    const int tid = threadIdx.x;
    const int w = tid >> 6, l = tid & 63;
    const unsigned short* PgC = Pg + (size_t)chain * CC * 4096;
    const int* EgC = Eg + chain * CC;
    const float* fbase = feats + (size_t)chain * SS * TT;

    // chain length L (per-wave, redundant)
    int msum = 0;
#pragma unroll
    for (int k = 0; k < 8; ++k) msum += mask[chain * SS + 64 * k + l];
#pragma unroll
    for (int m = 1; m < 64; m <<= 1) msum += __shfl_xor(msum, m, 64);
    const int L = msum;

    // gold partial: 2 positions per thread
    float g = 0.f;
#pragma unroll
    for (int rep = 0; rep < 2; ++rep) {
        int t = tid + rep * 256;
        if (t < L) {
            int cur = tags[chain * SS + t];
            int prev = t ? tags[chain * SS + t - 1] : START_TAG;
            g += fbase[(size_t)t * TT + cur] + trans[prev * TT + cur];
        }
    }
    g = wfsum64(g);
    if (l == 0) gred[w] = g;

    // p0 (all waves redundantly; identical values)
    float pl = fbase[l] + trans[START_TAG * TT + l];
    float M0 = wfmax64(pl);
    float x = __builtin_amdgcn_exp2f((pl - M0) * LOG2E_F);
    int exX = 0;

    // pipelined matvec chain over CC chunk matrices (scalar exponent per chunk)
    uint4 hA[8], hB[8];
    loadrow(hA, PgC, 0, l);
#pragma unroll
    for (int c = 0; c < CC; c += 2) {
        loadrow(hB, PgC, c + 1, l);
        mvstep(hA, EgC[c], &xsh[w][0], l, x, exX);
        if (c + 2 < CC) loadrow(hA, PgC, c + 2, l);
        mvstep(hB, EgC[c + 1], &xsh[w][0], l, x, exX);
    }

    // final contraction: fwd = log( sum_l x[l]*exp(trans[l][END]) ) + exX*ln2 + M0
    float val = x * expf(trans[l * TT + END_TAG]);
    val = wfsum64(val);
    float fwd = logf(val) + (float)exX * LN2_F + M0;

    __syncthreads();  // gred ready
    if (tid == 0) {
        float gold = gred[0] + gred[1] + gred[2] + gred[3] +
                     trans[tags[chain * SS + L - 1] * TT + END_TAG];
        atomicAdd(out, fwd - gold);
    }
}

extern "C" void kernel_launch(void* const* d_in, const int* in_sizes, int n_in,
                              void* d_out, int out_size, void* d_ws, size_t ws_size,
                              hipStream_t stream) {
    const float* feats = (const float*)d_in[0];
    const float* trans = (const float*)d_in[1];
    const int*   mask  = (const int*)d_in[2];
    const int*   tags  = (const int*)d_in[3];
    float* out = (float*)d_out;
    unsigned short* Pg = (unsigned short*)d_ws;
    int*       Eg = (int*)((char*)d_ws + WS_ECOL_OFF);

    crf_chunks<<<dim3(64 * CC), dim3(256), 0, stream>>>(feats, trans, mask, Pg, Eg, out);
    crf_combine<<<dim3(64), dim3(256), 0, stream>>>(feats, trans, mask, tags, Pg, Eg, out);
}